// Round 1
// baseline (1155.140 us; speedup 1.0000x reference)
//
#include <hip/hip_runtime.h>
#include <hip/hip_bf16.h>

#define BQ 256
#define TQ 1024
#define FQ 37
#define UQ 64
#define G3 192   // 3*U gate width
#define CH 8     // timesteps staged per chunk

__device__ __forceinline__ float sigmoid_f(float x) {
    return 1.0f / (1.0f + __expf(-x));
}

__global__ __launch_bounds__(G3, 1) void gru_fused_kernel(
    const float* __restrict__ values,      // [B,T,F]
    const int*   __restrict__ lengths,     // [B]
    const float* __restrict__ Wk,          // [F,3U]
    const float* __restrict__ Wr,          // [U,3U]
    const float* __restrict__ bias,        // [2,3U]
    const float* __restrict__ dw,          // [U,1]
    const float* __restrict__ db,          // [1]
    float*       __restrict__ out)         // [B,T,1]
{
    const int b = blockIdx.x;
    const int j = threadIdx.x;             // 0..191 -> gate column

    __shared__ float h_lds[UQ];            // hidden state
    __shared__ float s_x[G3];              // x-projection this step
    __shared__ float s_hp[G3];             // recurrent projection this step
    __shared__ float s_val[CH * FQ];       // staged input chunk
    __shared__ float s_w[UQ];              // dense weights

    // --- load per-column weights into registers (reused 1024x) ---
    float Rc[UQ];
#pragma unroll
    for (int u = 0; u < UQ; ++u) Rc[u] = Wr[u * G3 + j];
    float Kc[FQ];
#pragma unroll
    for (int f = 0; f < FQ; ++f) Kc[f] = Wk[f * G3 + j];
    const float b0 = bias[j];
    const float b1 = bias[G3 + j];
    const float dbias = db[0];

    if (j < UQ) { h_lds[j] = 0.0f; s_w[j] = dw[j]; }

    const int len = lengths[b];
    const float* vb = values + (size_t)b * TQ * FQ;
    float* ob = out + (size_t)b * TQ;

    __syncthreads();

    for (int t = 0; t < TQ; ++t) {
        const int tc = t & (CH - 1);
        if (tc == 0) {
            // stage CH timesteps of input features (coalesced)
            for (int idx = j; idx < CH * FQ; idx += G3)
                s_val[idx] = vb[t * FQ + idx];
            __syncthreads();
        }

        // ---- projections: thread j computes column j of x@K and h@R ----
        const float* xv = &s_val[tc * FQ];
        float xp = b0;
#pragma unroll
        for (int f = 0; f < FQ; ++f) xp += xv[f] * Kc[f];

        float hp0 = 0.f, hp1 = 0.f, hp2 = 0.f, hp3 = 0.f;
        const float4* h4 = (const float4*)h_lds;
#pragma unroll
        for (int u4 = 0; u4 < UQ / 4; ++u4) {
            float4 hv = h4[u4];
            hp0 += hv.x * Rc[4 * u4 + 0];
            hp1 += hv.y * Rc[4 * u4 + 1];
            hp2 += hv.z * Rc[4 * u4 + 2];
            hp3 += hv.w * Rc[4 * u4 + 3];
        }
        s_x[j]  = xp;
        s_hp[j] = b1 + ((hp0 + hp1) + (hp2 + hp3));
        __syncthreads();

        // ---- gates + state update + fused dense head (wave 0 only) ----
        if (j < UQ) {
            float z = sigmoid_f(s_x[j]        + s_hp[j]);
            float r = sigmoid_f(s_x[UQ + j]   + s_hp[UQ + j]);
            // tanh via exp: tanh(x) = 1 - 2/(exp(2x)+1)
            float ca = s_x[2 * UQ + j] + r * s_hp[2 * UQ + j];
            float c = 1.0f - 2.0f / (__expf(2.0f * ca) + 1.0f);
            float hj = h_lds[j];
            float hn = z * hj + (1.0f - z) * c;
            if (t < len) hj = hn;              // Keras masking: keep old state past length
            h_lds[j] = hj;

            // dense(1) + sigmoid, reduced across the wave
            float p = hj * s_w[j];
#pragma unroll
            for (int off = 32; off > 0; off >>= 1) p += __shfl_xor(p, off, 64);
            if (j == 0) ob[t] = sigmoid_f(p + dbias);
        }
        __syncthreads();
    }
}

extern "C" void kernel_launch(void* const* d_in, const int* in_sizes, int n_in,
                              void* d_out, int out_size, void* d_ws, size_t ws_size,
                              hipStream_t stream) {
    // setup_inputs order:
    // 0 demo (unused), 1 times (unused), 2 values, 3 measurements (unused),
    // 4 lengths, 5 kernel, 6 recurrent_kernel, 7 bias, 8 dense_w, 9 dense_b
    const float* values  = (const float*)d_in[2];
    const int*   lengths = (const int*)  d_in[4];
    const float* Wk      = (const float*)d_in[5];
    const float* Wr      = (const float*)d_in[6];
    const float* bias    = (const float*)d_in[7];
    const float* dw      = (const float*)d_in[8];
    const float* db      = (const float*)d_in[9];
    float* out = (float*)d_out;

    gru_fused_kernel<<<dim3(BQ), dim3(G3), 0, stream>>>(
        values, lengths, Wk, Wr, bias, dw, db, out);
}

// Round 2
// 1004.156 us; speedup vs baseline: 1.1504x; 1.1504x over previous
//
#include <hip/hip_runtime.h>
#include <hip/hip_bf16.h>

#define BQ 256
#define TQ 1024
#define FQ 37
#define UQ 64
#define G3 192   // 3*U gate width
#define CH 8     // timesteps staged per chunk
#define FP 40    // padded feature row (160B, float4-aligned)

__device__ __forceinline__ float sigmoid_f(float x) {
    return 1.0f / (1.0f + __expf(-x));
}
__device__ __forceinline__ float tanh_f(float x) {
    return 1.0f - 2.0f / (__expf(2.0f * x) + 1.0f);
}

// ---------------- Pass 1: recurrence, h kept in registers of all 3 waves ----
__global__ __launch_bounds__(G3, 1) void gru_rec_kernel(
    const float* __restrict__ values,      // [B,T,F]
    const int*   __restrict__ lengths,     // [B]
    const float* __restrict__ Wk,          // [F,3U]
    const float* __restrict__ Wr,          // [U,3U]
    const float* __restrict__ bias,        // [2,3U]
    float*       __restrict__ hs)          // [B,T,U] workspace
{
    const int b  = blockIdx.x;
    const int cj = threadIdx.x;            // gate column 0..191
    const int j  = cj & 63;                // lane
    const int w  = cj >> 6;                // wave = gate index (0:z 1:r 2:h)

    __shared__ __align__(16) float s_val[CH][FP];  // staged inputs
    __shared__ float s_a[2][G3];           // z,r pre-act sums; x-part of h gate
    __shared__ float s_b[2][UQ];           // recurrent part of h gate

    // per-column weights in registers (reused 1024x)
    float Rc[UQ];
#pragma unroll
    for (int u = 0; u < UQ; ++u) Rc[u] = Wr[u * G3 + cj];
    float Kc[FQ];
#pragma unroll
    for (int f = 0; f < FQ; ++f) Kc[f] = Wk[f * G3 + cj];
    const float b0 = bias[cj];
    const float b1 = bias[G3 + cj];
    const int len = lengths[b];
    const float* vb = values + (size_t)b * TQ * FQ;
    float* hb = hs + (size_t)b * TQ * UQ;

    float h = 0.0f;                        // every wave keeps full h (lane j = h_j)

    for (int t = 0; t < TQ; ++t) {
        const int tc = t & (CH - 1);
        if (tc == 0) {
            // stage CH timesteps of input features (coalesced)
            for (int idx = cj; idx < CH * FQ; idx += G3) {
                int r = idx / FQ, c = idx - r * FQ;
                s_val[r][c] = vb[t * FQ + idx];
            }
            asm volatile("s_waitcnt vmcnt(0) lgkmcnt(0)" ::: "memory");
            __builtin_amdgcn_s_barrier();
        }

        // ---- phase A: recurrent GEMV via readlane broadcast of register h ----
        const int hbits = __float_as_int(h);
        float hp0 = 0.f, hp1 = 0.f, hp2 = 0.f, hp3 = 0.f;
#pragma unroll
        for (int u = 0; u < UQ; u += 4) {
            float h0 = __int_as_float(__builtin_amdgcn_readlane(hbits, u + 0));
            float h1 = __int_as_float(__builtin_amdgcn_readlane(hbits, u + 1));
            float h2 = __int_as_float(__builtin_amdgcn_readlane(hbits, u + 2));
            float h3 = __int_as_float(__builtin_amdgcn_readlane(hbits, u + 3));
            hp0 += h0 * Rc[u + 0];
            hp1 += h1 * Rc[u + 1];
            hp2 += h2 * Rc[u + 2];
            hp3 += h3 * Rc[u + 3];
        }
        const float hp = b1 + ((hp0 + hp1) + (hp2 + hp3));

        // x-projection (independent of h; scheduler can overlap)
        float x0 = 0.f, x1 = 0.f, x2 = 0.f, x3 = 0.f;
        const float4* xv4 = (const float4*)(&s_val[tc][0]);
#pragma unroll
        for (int k = 0; k < 9; ++k) {
            float4 v = xv4[k];
            x0 += v.x * Kc[4 * k + 0];
            x1 += v.y * Kc[4 * k + 1];
            x2 += v.z * Kc[4 * k + 2];
            x3 += v.w * Kc[4 * k + 3];
        }
        const float xp = b0 + ((x0 + x1) + (x2 + x3)) + s_val[tc][36] * Kc[36];

        // ---- exchange gate pre-activations (double-buffered, 1 barrier) ----
        const int buf = t & 1;
        if (w == 0)      s_a[buf][j]       = xp + hp;   // z
        else if (w == 1) s_a[buf][64 + j]  = xp + hp;   // r
        else { s_a[buf][128 + j] = xp; s_b[buf][j] = hp; }  // h gate: keep split
        asm volatile("s_waitcnt lgkmcnt(0)" ::: "memory");
        __builtin_amdgcn_s_barrier();

        // ---- phase B: gates + update, redundantly on all 3 waves ----
        const float az = s_a[buf][j];
        const float ar = s_a[buf][64 + j];
        const float ax = s_a[buf][128 + j];
        const float hh = s_b[buf][j];
        const float z = sigmoid_f(az);
        const float r = sigmoid_f(ar);
        const float c = tanh_f(ax + r * hh);
        const float hn = z * h + (1.0f - z) * c;
        h = (t < len) ? hn : h;            // Keras masking (len uniform per block)

        if (w == 1) hb[t * UQ + j] = h;    // fire-and-forget (no vmcnt wait here)
    }
}

// ---------------- Pass 2: dense(1)+sigmoid head, one wave per (b,t) ---------
__global__ __launch_bounds__(256) void head_kernel(
    const float* __restrict__ hs,          // [B*T, U]
    const float* __restrict__ dw,          // [U]
    const float* __restrict__ db,          // [1]
    float*       __restrict__ out,         // [B*T]
    int total)
{
    const int wid  = (int)((blockIdx.x * blockDim.x + threadIdx.x) >> 6);
    const int lane = threadIdx.x & 63;
    if (wid >= total) return;
    float p = hs[(size_t)wid * UQ + lane] * dw[lane];
#pragma unroll
    for (int off = 32; off > 0; off >>= 1) p += __shfl_xor(p, off, 64);
    if (lane == 0) out[wid] = sigmoid_f(p + db[0]);
}

// ---------------- Fallback: fully fused (if workspace too small) ------------
__global__ __launch_bounds__(G3, 1) void gru_fused_kernel(
    const float* __restrict__ values, const int* __restrict__ lengths,
    const float* __restrict__ Wk, const float* __restrict__ Wr,
    const float* __restrict__ bias, const float* __restrict__ dw,
    const float* __restrict__ db, float* __restrict__ out)
{
    const int b = blockIdx.x;
    const int j = threadIdx.x;
    __shared__ float h_lds[UQ];
    __shared__ float s_x[G3];
    __shared__ float s_hp[G3];
    __shared__ float s_val[CH * FQ];
    __shared__ float s_w[UQ];
    float Rc[UQ];
#pragma unroll
    for (int u = 0; u < UQ; ++u) Rc[u] = Wr[u * G3 + j];
    float Kc[FQ];
#pragma unroll
    for (int f = 0; f < FQ; ++f) Kc[f] = Wk[f * G3 + j];
    const float b0 = bias[j];
    const float b1 = bias[G3 + j];
    const float dbias = db[0];
    if (j < UQ) { h_lds[j] = 0.0f; s_w[j] = dw[j]; }
    const int len = lengths[b];
    const float* vb = values + (size_t)b * TQ * FQ;
    float* ob = out + (size_t)b * TQ;
    __syncthreads();
    for (int t = 0; t < TQ; ++t) {
        const int tc = t & (CH - 1);
        if (tc == 0) {
            for (int idx = j; idx < CH * FQ; idx += G3)
                s_val[idx] = vb[t * FQ + idx];
            __syncthreads();
        }
        const float* xv = &s_val[tc * FQ];
        float xp = b0;
#pragma unroll
        for (int f = 0; f < FQ; ++f) xp += xv[f] * Kc[f];
        float hp0 = 0.f, hp1 = 0.f, hp2 = 0.f, hp3 = 0.f;
        const float4* h4 = (const float4*)h_lds;
#pragma unroll
        for (int u4 = 0; u4 < UQ / 4; ++u4) {
            float4 hv = h4[u4];
            hp0 += hv.x * Rc[4 * u4 + 0];
            hp1 += hv.y * Rc[4 * u4 + 1];
            hp2 += hv.z * Rc[4 * u4 + 2];
            hp3 += hv.w * Rc[4 * u4 + 3];
        }
        s_x[j] = xp;
        s_hp[j] = b1 + ((hp0 + hp1) + (hp2 + hp3));
        __syncthreads();
        if (j < UQ) {
            float z = sigmoid_f(s_x[j] + s_hp[j]);
            float r = sigmoid_f(s_x[UQ + j] + s_hp[UQ + j]);
            float ca = s_x[2 * UQ + j] + r * s_hp[2 * UQ + j];
            float c = 1.0f - 2.0f / (__expf(2.0f * ca) + 1.0f);
            float hj = h_lds[j];
            float hn = z * hj + (1.0f - z) * c;
            if (t < len) hj = hn;
            h_lds[j] = hj;
            float p = hj * s_w[j];
#pragma unroll
            for (int off = 32; off > 0; off >>= 1) p += __shfl_xor(p, off, 64);
            if (j == 0) ob[t] = sigmoid_f(p + dbias);
        }
        __syncthreads();
    }
}

extern "C" void kernel_launch(void* const* d_in, const int* in_sizes, int n_in,
                              void* d_out, int out_size, void* d_ws, size_t ws_size,
                              hipStream_t stream) {
    const float* values  = (const float*)d_in[2];
    const int*   lengths = (const int*)  d_in[4];
    const float* Wk      = (const float*)d_in[5];
    const float* Wr      = (const float*)d_in[6];
    const float* bias    = (const float*)d_in[7];
    const float* dw      = (const float*)d_in[8];
    const float* db      = (const float*)d_in[9];
    float* out = (float*)d_out;

    const size_t need = (size_t)BQ * TQ * UQ * sizeof(float);  // 64 MB
    if (ws_size >= need) {
        float* hs = (float*)d_ws;
        gru_rec_kernel<<<dim3(BQ), dim3(G3), 0, stream>>>(
            values, lengths, Wk, Wr, bias, hs);
        const int total = BQ * TQ;            // one wave per (b,t)
        const int blocks = total / 4;         // 4 waves per 256-thread block
        head_kernel<<<dim3(blocks), dim3(256), 0, stream>>>(
            hs, dw, db, out, total);
    } else {
        gru_fused_kernel<<<dim3(BQ), dim3(G3), 0, stream>>>(
            values, lengths, Wk, Wr, bias, dw, db, out);
    }
}

// Round 3
// 984.814 us; speedup vs baseline: 1.1730x; 1.0196x over previous
//
#include <hip/hip_runtime.h>
#include <hip/hip_bf16.h>

#define BQ 256
#define TQ 1024
#define FQ 37
#define UQ 64
#define G3 192   // 3*U gate width
#define CH 8     // timesteps staged per chunk
#define FP 40    // padded feature row (160B, float4-aligned)

__device__ __forceinline__ float sigmoid_f(float x) {
    return 1.0f / (1.0f + __expf(-x));
}
__device__ __forceinline__ float tanh_f(float x) {
    return 1.0f - 2.0f / (__expf(2.0f * x) + 1.0f);
}

// ---------------- Pass 1: recurrence, h kept in registers of all 3 waves ----
__global__ __launch_bounds__(G3, 1) void gru_rec_kernel(
    const float* __restrict__ values,      // [B,T,F]
    const int*   __restrict__ lengths,     // [B]
    const float* __restrict__ Wk,          // [F,3U]
    const float* __restrict__ Wr,          // [U,3U]
    const float* __restrict__ bias,        // [2,3U]
    float*       __restrict__ hs)          // [B,T,U] workspace
{
    const int b  = blockIdx.x;
    const int cj = threadIdx.x;            // gate column 0..191
    const int j  = cj & 63;                // lane
    const int w  = cj >> 6;                // wave = gate index (0:z 1:r 2:h)

    __shared__ __align__(16) float s_val[CH][FP];  // staged inputs
    __shared__ float s_z[2][UQ];           // sigmoid(z pre-act)
    __shared__ float s_r[2][UQ];           // sigmoid(r pre-act)
    __shared__ float s_ax[2][UQ];          // x-part of h gate
    __shared__ float s_hh[2][UQ];          // recurrent part of h gate

    // ---- per-column weights into registers, PINNED so the compiler cannot
    // rematerialize the loads inside the loop (R1: VGPR=64 meant weights were
    // re-fetched from L2 every step, ~77KB/step/CU — the whole bottleneck) ----
    float Rc[UQ];
#pragma unroll
    for (int u = 0; u < UQ; ++u) Rc[u] = Wr[u * G3 + cj];
#pragma unroll
    for (int u = 0; u < UQ; u += 4)
        asm volatile("" : "+v"(Rc[u]), "+v"(Rc[u+1]), "+v"(Rc[u+2]), "+v"(Rc[u+3]));

    float Kc[FQ];
#pragma unroll
    for (int f = 0; f < FQ; ++f) Kc[f] = Wk[f * G3 + cj];
#pragma unroll
    for (int f = 0; f < 36; f += 4)
        asm volatile("" : "+v"(Kc[f]), "+v"(Kc[f+1]), "+v"(Kc[f+2]), "+v"(Kc[f+3]));
    asm volatile("" : "+v"(Kc[36]));

    float b0 = bias[cj];
    float b1 = bias[G3 + cj];
    asm volatile("" : "+v"(b0), "+v"(b1));

    const int len = lengths[b];
    const float* vb = values + (size_t)b * TQ * FQ;
    float* hb = hs + (size_t)b * TQ * UQ;

    float h = 0.0f;                        // every wave keeps full h (lane j = h_j)

    for (int t = 0; t < TQ; ++t) {
        const int tc = t & (CH - 1);
        if (tc == 0) {
            // stage CH timesteps of input features (coalesced)
            for (int idx = cj; idx < CH * FQ; idx += G3) {
                int r = idx / FQ, c = idx - r * FQ;
                s_val[r][c] = vb[t * FQ + idx];
            }
            asm volatile("s_waitcnt vmcnt(0) lgkmcnt(0)" ::: "memory");
            __builtin_amdgcn_sched_barrier(0);
            __builtin_amdgcn_s_barrier();
            __builtin_amdgcn_sched_barrier(0);
        }

        // ---- phase A: recurrent GEMV via readlane broadcast of register h ----
        const int hbits = __float_as_int(h);
        float hp0 = 0.f, hp1 = 0.f, hp2 = 0.f, hp3 = 0.f;
#pragma unroll
        for (int u = 0; u < UQ; u += 4) {
            float h0 = __int_as_float(__builtin_amdgcn_readlane(hbits, u + 0));
            float h1 = __int_as_float(__builtin_amdgcn_readlane(hbits, u + 1));
            float h2 = __int_as_float(__builtin_amdgcn_readlane(hbits, u + 2));
            float h3 = __int_as_float(__builtin_amdgcn_readlane(hbits, u + 3));
            hp0 += h0 * Rc[u + 0];
            hp1 += h1 * Rc[u + 1];
            hp2 += h2 * Rc[u + 2];
            hp3 += h3 * Rc[u + 3];
        }
        const float hp = b1 + ((hp0 + hp1) + (hp2 + hp3));

        // x-projection (independent of h; scheduler overlaps with readlanes)
        float x0 = 0.f, x1 = 0.f, x2 = 0.f, x3 = 0.f;
        const float4* xv4 = (const float4*)(&s_val[tc][0]);
#pragma unroll
        for (int k = 0; k < 9; ++k) {
            float4 v = xv4[k];
            x0 += v.x * Kc[4 * k + 0];
            x1 += v.y * Kc[4 * k + 1];
            x2 += v.z * Kc[4 * k + 2];
            x3 += v.w * Kc[4 * k + 3];
        }
        const float xp = b0 + ((x0 + x1) + (x2 + x3)) + s_val[tc][36] * Kc[36];

        // ---- exchange (double-buffered, one raw barrier, no vmcnt drain) ----
        const int buf = t & 1;
        if (w == 0)      s_z[buf][j] = sigmoid_f(xp + hp);   // z, pre-activated
        else if (w == 1) s_r[buf][j] = sigmoid_f(xp + hp);   // r, pre-activated
        else { s_ax[buf][j] = xp; s_hh[buf][j] = hp; }       // h gate, split
        asm volatile("s_waitcnt lgkmcnt(0)" ::: "memory");
        __builtin_amdgcn_sched_barrier(0);
        __builtin_amdgcn_s_barrier();
        __builtin_amdgcn_sched_barrier(0);

        // ---- phase B: state update, redundantly on all 3 waves ----
        const float z  = s_z[buf][j];
        const float r  = s_r[buf][j];
        const float ax = s_ax[buf][j];
        const float hh = s_hh[buf][j];
        const float c  = tanh_f(ax + r * hh);
        const float hn = z * h + (1.0f - z) * c;
        h = (t < len) ? hn : h;            // Keras masking (len uniform per block)

        if (w == 0) hb[t * UQ + j] = h;    // fire-and-forget (no vmcnt wait here)
    }
}

// ---------------- Pass 2: dense(1)+sigmoid head, one wave per (b,t) ---------
__global__ __launch_bounds__(256) void head_kernel(
    const float* __restrict__ hs,          // [B*T, U]
    const float* __restrict__ dw,          // [U]
    const float* __restrict__ db,          // [1]
    float*       __restrict__ out,         // [B*T]
    int total)
{
    const int wid  = (int)((blockIdx.x * blockDim.x + threadIdx.x) >> 6);
    const int lane = threadIdx.x & 63;
    if (wid >= total) return;
    float p = hs[(size_t)wid * UQ + lane] * dw[lane];
#pragma unroll
    for (int off = 32; off > 0; off >>= 1) p += __shfl_xor(p, off, 64);
    if (lane == 0) out[wid] = sigmoid_f(p + db[0]);
}

// ---------------- Fallback: fully fused (if workspace too small) ------------
__global__ __launch_bounds__(G3, 1) void gru_fused_kernel(
    const float* __restrict__ values, const int* __restrict__ lengths,
    const float* __restrict__ Wk, const float* __restrict__ Wr,
    const float* __restrict__ bias, const float* __restrict__ dw,
    const float* __restrict__ db, float* __restrict__ out)
{
    const int b = blockIdx.x;
    const int j = threadIdx.x;
    __shared__ float h_lds[UQ];
    __shared__ float s_x[G3];
    __shared__ float s_hp[G3];
    __shared__ float s_val[CH * FQ];
    __shared__ float s_w[UQ];
    float Rc[UQ];
#pragma unroll
    for (int u = 0; u < UQ; ++u) Rc[u] = Wr[u * G3 + j];
    float Kc[FQ];
#pragma unroll
    for (int f = 0; f < FQ; ++f) Kc[f] = Wk[f * G3 + j];
    const float b0 = bias[j];
    const float b1 = bias[G3 + j];
    const float dbias = db[0];
    if (j < UQ) { h_lds[j] = 0.0f; s_w[j] = dw[j]; }
    const int len = lengths[b];
    const float* vb = values + (size_t)b * TQ * FQ;
    float* ob = out + (size_t)b * TQ;
    __syncthreads();
    for (int t = 0; t < TQ; ++t) {
        const int tc = t & (CH - 1);
        if (tc == 0) {
            for (int idx = j; idx < CH * FQ; idx += G3)
                s_val[idx] = vb[t * FQ + idx];
            __syncthreads();
        }
        const float* xv = &s_val[tc * FQ];
        float xp = b0;
#pragma unroll
        for (int f = 0; f < FQ; ++f) xp += xv[f] * Kc[f];
        float hp0 = 0.f, hp1 = 0.f, hp2 = 0.f, hp3 = 0.f;
        const float4* h4 = (const float4*)h_lds;
#pragma unroll
        for (int u4 = 0; u4 < UQ / 4; ++u4) {
            float4 hv = h4[u4];
            hp0 += hv.x * Rc[4 * u4 + 0];
            hp1 += hv.y * Rc[4 * u4 + 1];
            hp2 += hv.z * Rc[4 * u4 + 2];
            hp3 += hv.w * Rc[4 * u4 + 3];
        }
        s_x[j] = xp;
        s_hp[j] = b1 + ((hp0 + hp1) + (hp2 + hp3));
        __syncthreads();
        if (j < UQ) {
            float z = sigmoid_f(s_x[j] + s_hp[j]);
            float r = sigmoid_f(s_x[UQ + j] + s_hp[UQ + j]);
            float ca = s_x[2 * UQ + j] + r * s_hp[2 * UQ + j];
            float c = 1.0f - 2.0f / (__expf(2.0f * ca) + 1.0f);
            float hj = h_lds[j];
            float hn = z * hj + (1.0f - z) * c;
            if (t < len) hj = hn;
            h_lds[j] = hj;
            float p = hj * s_w[j];
#pragma unroll
            for (int off = 32; off > 0; off >>= 1) p += __shfl_xor(p, off, 64);
            if (j == 0) ob[t] = sigmoid_f(p + dbias);
        }
        __syncthreads();
    }
}

extern "C" void kernel_launch(void* const* d_in, const int* in_sizes, int n_in,
                              void* d_out, int out_size, void* d_ws, size_t ws_size,
                              hipStream_t stream) {
    const float* values  = (const float*)d_in[2];
    const int*   lengths = (const int*)  d_in[4];
    const float* Wk      = (const float*)d_in[5];
    const float* Wr      = (const float*)d_in[6];
    const float* bias    = (const float*)d_in[7];
    const float* dw      = (const float*)d_in[8];
    const float* db      = (const float*)d_in[9];
    float* out = (float*)d_out;

    const size_t need = (size_t)BQ * TQ * UQ * sizeof(float);  // 64 MB
    if (ws_size >= need) {
        float* hs = (float*)d_ws;
        gru_rec_kernel<<<dim3(BQ), dim3(G3), 0, stream>>>(
            values, lengths, Wk, Wr, bias, hs);
        const int total = BQ * TQ;            // one wave per (b,t)
        const int blocks = total / 4;         // 4 waves per 256-thread block
        head_kernel<<<dim3(blocks), dim3(256), 0, stream>>>(
            hs, dw, db, out, total);
    } else {
        gru_fused_kernel<<<dim3(BQ), dim3(G3), 0, stream>>>(
            values, lengths, Wk, Wr, bias, dw, db, out);
    }
}

// Round 4
// 834.053 us; speedup vs baseline: 1.3850x; 1.1808x over previous
//
#include <hip/hip_runtime.h>
#include <hip/hip_bf16.h>

#define BQ 256
#define TQ 1024
#define FQ 37
#define UQ 64
#define G3 192   // 3*U gate width
#define CH 8     // timesteps per staged chunk
#define BLK 384  // 6 waves

__device__ __forceinline__ float sigmoid_f(float x) {
    return 1.0f / (1.0f + __expf(-x));
}
__device__ __forceinline__ float tanh_f(float x) {
    return 1.0f - 2.0f / (__expf(2.0f * x) + 1.0f);
}

// ---------------- Pass 1: recurrence -----------------------------------------
// 6 waves: wave w -> gate g=w>>1 (0:z 1:r 2:h), h-half hf=w&1.
// Thread holds 32 Wr weights (half a column) -> total regs ~50 < the 64-VGPR
// allocation the compiler insists on (R1-R3: 101 resident weights => spill).
// x-projection computed in 8-step bursts from LDS-resident Wk (no Kc regs).
__global__ __launch_bounds__(BLK, 1) void gru_rec6(
    const float* __restrict__ values,      // [B,T,F]
    const int*   __restrict__ lengths,     // [B]
    const float* __restrict__ Wk,          // [F,3U]
    const float* __restrict__ Wr,          // [U,3U]
    const float* __restrict__ bias,        // [2,3U]
    float*       __restrict__ hs)          // [B,T,U] workspace
{
    const int tid = threadIdx.x;
    const int j   = tid & 63;
    const int w   = tid >> 6;
    const int g   = w >> 1;                // gate
    const int hf  = w & 1;                 // h-half
    const int c   = (g << 6) | j;          // gate column 0..191
    const int b   = blockIdx.x;

    __shared__ float s_wk[FQ][G3];                   // 28.4 KB, loaded once
    __shared__ float s_b0[G3];
    __shared__ __align__(16) float s_v[2][CH][40];   // staged input chunks
    __shared__ float s_xp[CH][G3];                   // burst-computed x-proj
    __shared__ float s_part[2][6][UQ];               // gate partials (dbuf)

    // 32 recurrent weights: rows [32*hf, 32*hf+32) of column c
    float Rc[32];
#pragma unroll
    for (int i = 0; i < 32; ++i) Rc[i] = Wr[(hf * 32 + i) * G3 + c];
    const float b1 = (hf == 0) ? bias[G3 + c] : 0.0f;   // recurrent bias

    for (int idx = tid; idx < FQ * G3; idx += BLK) (&s_wk[0][0])[idx] = Wk[idx];
    if (tid < G3) s_b0[tid] = bias[tid];

    const int len = lengths[b];
    const float* vbp = values + (size_t)b * TQ * FQ;
    float* hb = hs + (size_t)b * TQ * UQ;

    // stage chunk 0 into regs (296 dwords, threads 0..295)
    const int srow = tid / FQ, scol = tid - srow * FQ;
    const bool st_act = tid < CH * FQ;
    float stage = 0.0f;
    if (st_act) stage = vbp[srow * FQ + scol];

    asm volatile("s_waitcnt vmcnt(0) lgkmcnt(0)" ::: "memory");
    __builtin_amdgcn_s_barrier();          // s_wk/s_b0 visible, stage arrived

    const int cb_ = tid % G3;              // burst column
    const int g4  = (tid / G3) * 4;        // burst row base (0 or 4)

    float h = 0.0f;                        // lane j holds h_j, in EVERY wave

    for (int t = 0; t < TQ; ++t) {
        const int tc  = t & (CH - 1);
        const int buf = t & 1;

        if (tc == 0) {
            const int vb2 = (t >> 3) & 1;
            // prefetched chunk arrived ~8 steps ago; also drains h-stores
            asm volatile("s_waitcnt vmcnt(0)" ::: "memory");
            if (st_act) s_v[vb2][srow][scol] = stage;
            if (st_act && (t + CH < TQ))
                stage = vbp[(t + CH + srow) * FQ + scol];   // issue-early
            asm volatile("s_waitcnt lgkmcnt(0)" ::: "memory");
            __builtin_amdgcn_s_barrier();                    // s_v visible

            // ---- burst: xp[tc][c] for the 8 steps of this chunk ----
            // thread -> (rows g4..g4+3, col cb_); k-pairs to cap VGPR use
            {
                const float bb = s_b0[cb_];
                float a0 = bb, a1 = bb;
#pragma unroll
                for (int f4 = 0; f4 < 9; ++f4) {
                    float4 v0 = *(const float4*)&s_v[vb2][g4 + 0][f4 * 4];
                    float4 v1 = *(const float4*)&s_v[vb2][g4 + 1][f4 * 4];
#pragma unroll
                    for (int e = 0; e < 4; ++e) {
                        const float wkv = s_wk[f4 * 4 + e][cb_];
                        a0 += wkv * ((const float*)&v0)[e];
                        a1 += wkv * ((const float*)&v1)[e];
                    }
                }
                {
                    const float wkv = s_wk[36][cb_];
                    a0 += wkv * s_v[vb2][g4 + 0][36];
                    a1 += wkv * s_v[vb2][g4 + 1][36];
                }
                s_xp[g4 + 0][cb_] = a0;
                s_xp[g4 + 1][cb_] = a1;

                float a2 = bb, a3 = bb;
#pragma unroll
                for (int f4 = 0; f4 < 9; ++f4) {
                    float4 v2 = *(const float4*)&s_v[vb2][g4 + 2][f4 * 4];
                    float4 v3 = *(const float4*)&s_v[vb2][g4 + 3][f4 * 4];
#pragma unroll
                    for (int e = 0; e < 4; ++e) {
                        const float wkv = s_wk[f4 * 4 + e][cb_];
                        a2 += wkv * ((const float*)&v2)[e];
                        a3 += wkv * ((const float*)&v3)[e];
                    }
                }
                {
                    const float wkv = s_wk[36][cb_];
                    a2 += wkv * s_v[vb2][g4 + 2][36];
                    a3 += wkv * s_v[vb2][g4 + 3][36];
                }
                s_xp[g4 + 2][cb_] = a2;
                s_xp[g4 + 3][cb_] = a3;
            }
            asm volatile("s_waitcnt lgkmcnt(0)" ::: "memory");
            __builtin_amdgcn_s_barrier();                    // s_xp visible
        }

        // ---- phase A: half-GEMV via readlane broadcast of register h ----
        float p0 = 0.f, p1 = 0.f, p2 = 0.f, p3 = 0.f;
        const int hbits = __float_as_int(h);
        if (hf == 0) {
#pragma unroll
            for (int i = 0; i < 32; i += 4) {
                p0 += __int_as_float(__builtin_amdgcn_readlane(hbits, i + 0)) * Rc[i + 0];
                p1 += __int_as_float(__builtin_amdgcn_readlane(hbits, i + 1)) * Rc[i + 1];
                p2 += __int_as_float(__builtin_amdgcn_readlane(hbits, i + 2)) * Rc[i + 2];
                p3 += __int_as_float(__builtin_amdgcn_readlane(hbits, i + 3)) * Rc[i + 3];
            }
        } else {
#pragma unroll
            for (int i = 0; i < 32; i += 4) {
                p0 += __int_as_float(__builtin_amdgcn_readlane(hbits, 32 + i + 0)) * Rc[i + 0];
                p1 += __int_as_float(__builtin_amdgcn_readlane(hbits, 32 + i + 1)) * Rc[i + 1];
                p2 += __int_as_float(__builtin_amdgcn_readlane(hbits, 32 + i + 2)) * Rc[i + 2];
                p3 += __int_as_float(__builtin_amdgcn_readlane(hbits, 32 + i + 3)) * Rc[i + 3];
            }
        }
        float partial = (p0 + p1) + (p2 + p3);
        if (hf == 0) {
            partial += b1;
            if (g < 2) partial += s_xp[tc][c];   // fold x-part for z,r
        }
        s_part[buf][g * 2 + hf][j] = partial;
        asm volatile("s_waitcnt lgkmcnt(0)" ::: "memory");
        __builtin_amdgcn_s_barrier();

        // ---- phase B: gates + update, redundantly on all 6 waves ----
        const float z  = sigmoid_f(s_part[buf][0][j] + s_part[buf][1][j]);
        const float r  = sigmoid_f(s_part[buf][2][j] + s_part[buf][3][j]);
        const float hh = s_part[buf][4][j] + s_part[buf][5][j];
        const float xh = s_xp[tc][128 + j];
        const float cc = tanh_f(xh + r * hh);
        const float hn = z * h + (1.0f - z) * cc;
        h = (t < len) ? hn : h;                  // Keras masking

        if (w == 0) hb[t * UQ + j] = h;          // fire-and-forget
    }
}

// ---------------- Pass 2: dense(1)+sigmoid head, one wave per (b,t) ---------
__global__ __launch_bounds__(256) void head_kernel(
    const float* __restrict__ hs,          // [B*T, U]
    const float* __restrict__ dw,          // [U]
    const float* __restrict__ db,          // [1]
    float*       __restrict__ out,         // [B*T]
    int total)
{
    const int wid  = (int)((blockIdx.x * blockDim.x + threadIdx.x) >> 6);
    const int lane = threadIdx.x & 63;
    if (wid >= total) return;
    float p = hs[(size_t)wid * UQ + lane] * dw[lane];
#pragma unroll
    for (int off = 32; off > 0; off >>= 1) p += __shfl_xor(p, off, 64);
    if (lane == 0) out[wid] = sigmoid_f(p + db[0]);
}

// ---------------- Fallback: fully fused (if workspace too small) ------------
__global__ __launch_bounds__(G3, 1) void gru_fused_kernel(
    const float* __restrict__ values, const int* __restrict__ lengths,
    const float* __restrict__ Wk, const float* __restrict__ Wr,
    const float* __restrict__ bias, const float* __restrict__ dw,
    const float* __restrict__ db, float* __restrict__ out)
{
    const int b = blockIdx.x;
    const int j = threadIdx.x;
    __shared__ float h_lds[UQ];
    __shared__ float s_x[G3];
    __shared__ float s_hp[G3];
    __shared__ float s_val[CH * FQ];
    __shared__ float s_w[UQ];
    float Rc[UQ];
#pragma unroll
    for (int u = 0; u < UQ; ++u) Rc[u] = Wr[u * G3 + j];
    float Kc[FQ];
#pragma unroll
    for (int f = 0; f < FQ; ++f) Kc[f] = Wk[f * G3 + j];
    const float b0 = bias[j];
    const float b1 = bias[G3 + j];
    const float dbias = db[0];
    if (j < UQ) { h_lds[j] = 0.0f; s_w[j] = dw[j]; }
    const int len = lengths[b];
    const float* vb = values + (size_t)b * TQ * FQ;
    float* ob = out + (size_t)b * TQ;
    __syncthreads();
    for (int t = 0; t < TQ; ++t) {
        const int tc = t & (CH - 1);
        if (tc == 0) {
            for (int idx = j; idx < CH * FQ; idx += G3)
                s_val[idx] = vb[t * FQ + idx];
            __syncthreads();
        }
        const float* xv = &s_val[tc * FQ];
        float xp = b0;
#pragma unroll
        for (int f = 0; f < FQ; ++f) xp += xv[f] * Kc[f];
        float hp0 = 0.f, hp1 = 0.f, hp2 = 0.f, hp3 = 0.f;
        const float4* h4 = (const float4*)h_lds;
#pragma unroll
        for (int u4 = 0; u4 < UQ / 4; ++u4) {
            float4 hv = h4[u4];
            hp0 += hv.x * Rc[4 * u4 + 0];
            hp1 += hv.y * Rc[4 * u4 + 1];
            hp2 += hv.z * Rc[4 * u4 + 2];
            hp3 += hv.w * Rc[4 * u4 + 3];
        }
        s_x[j] = xp;
        s_hp[j] = b1 + ((hp0 + hp1) + (hp2 + hp3));
        __syncthreads();
        if (j < UQ) {
            float z = sigmoid_f(s_x[j] + s_hp[j]);
            float r = sigmoid_f(s_x[UQ + j] + s_hp[UQ + j]);
            float ca = s_x[2 * UQ + j] + r * s_hp[2 * UQ + j];
            float c = 1.0f - 2.0f / (__expf(2.0f * ca) + 1.0f);
            float hj = h_lds[j];
            float hn = z * hj + (1.0f - z) * c;
            if (t < len) hj = hn;
            h_lds[j] = hj;
            float p = hj * s_w[j];
#pragma unroll
            for (int off = 32; off > 0; off >>= 1) p += __shfl_xor(p, off, 64);
            if (j == 0) ob[t] = sigmoid_f(p + dbias);
        }
        __syncthreads();
    }
}

extern "C" void kernel_launch(void* const* d_in, const int* in_sizes, int n_in,
                              void* d_out, int out_size, void* d_ws, size_t ws_size,
                              hipStream_t stream) {
    const float* values  = (const float*)d_in[2];
    const int*   lengths = (const int*)  d_in[4];
    const float* Wk      = (const float*)d_in[5];
    const float* Wr      = (const float*)d_in[6];
    const float* bias    = (const float*)d_in[7];
    const float* dw      = (const float*)d_in[8];
    const float* db      = (const float*)d_in[9];
    float* out = (float*)d_out;

    const size_t need = (size_t)BQ * TQ * UQ * sizeof(float);  // 64 MB
    if (ws_size >= need) {
        float* hs = (float*)d_ws;
        gru_rec6<<<dim3(BQ), dim3(BLK), 0, stream>>>(
            values, lengths, Wk, Wr, bias, hs);
        const int total = BQ * TQ;            // one wave per (b,t)
        const int blocks = total / 4;         // 4 waves per 256-thread block
        head_kernel<<<dim3(blocks), dim3(256), 0, stream>>>(
            hs, dw, db, out, total);
    } else {
        gru_fused_kernel<<<dim3(BQ), dim3(G3), 0, stream>>>(
            values, lengths, Wk, Wr, bias, dw, db, out);
    }
}

// Round 5
// 768.732 us; speedup vs baseline: 1.5027x; 1.0850x over previous
//
#include <hip/hip_runtime.h>

#define BQ 256
#define TQ 1024
#define FQ 37
#define UQ 64
#define G3 192   // 3*U
#define CH 8     // timesteps per chunk
#define BLK 384  // 6 waves: (gate g = w>>1) x (k-half hf = w&1)

__device__ __forceinline__ float sigmoid_f(float x) {
    return 1.0f / (1.0f + __expf(-x));
}
__device__ __forceinline__ float tanh_f(float x) {
    return 1.0f - 2.0f / (__expf(2.0f * x) + 1.0f);
}

// One block per batch element. Per step:
//  phase A: h@R half-column via readlane broadcast (32 fma) + fold xp for z,r
//  slice:   1/8 of NEXT chunk's x-projection (Kc in regs, v broadcast b128)
//  exchange: 7 floats via double-buffered LDS, ONE raw barrier
//  phase B: gates + h update, redundant on all 6 waves (h stays in regs)
// Head (dense(1)+sigmoid) done per-chunk by wave 0 from LDS-staged h.
__global__ __launch_bounds__(BLK, 1) void gru_rec(
    const float* __restrict__ values,      // [B,T,F]
    const int*   __restrict__ lengths,     // [B]
    const float* __restrict__ Wk,          // [F,3U]
    const float* __restrict__ Wr,          // [U,3U]
    const float* __restrict__ bias,        // [2,3U]
    const float* __restrict__ dw,          // [U]
    const float* __restrict__ db,          // [1]
    float*       __restrict__ out)         // [B,T]
{
    const int tid = threadIdx.x;
    const int j   = tid & 63;
    const int w   = tid >> 6;
    const int g   = w >> 1;                // gate 0:z 1:r 2:h
    const int hf  = w & 1;                 // k-half / feature-half
    const int c   = (g << 6) | j;          // gate column 0..191
    const int b   = blockIdx.x;

    __shared__ __align__(16) float s_v[2][CH][40];     // v chunks (dbuf), padded
    __shared__ float s_xpp[2][2][CH][G3];              // xp partials [par][hf]
    __shared__ float s_part[2][7][UQ];                 // exchange (dbuf), +xh slot
    __shared__ float s_h8[CH][UQ];                     // h history for head

    // ---- weights in registers (R4 proved ~50 weight regs stay resident) ----
    float Rc[32];                          // rows [32*hf, 32*hf+32) of col c
#pragma unroll
    for (int i = 0; i < 32; ++i) Rc[i] = Wr[(hf * 32 + i) * G3 + c];

    float Kc[20];                          // feature-half: hf0 f0..19, hf1 f20..36
#pragma unroll
    for (int i = 0; i < 20; ++i) Kc[i] = 0.0f;
    if (hf == 0) {
#pragma unroll
        for (int i = 0; i < 20; ++i) Kc[i] = Wk[i * G3 + c];
    } else {
#pragma unroll
        for (int i = 0; i < 17; ++i) Kc[i] = Wk[(20 + i) * G3 + c];
    }
    const float b0 = (hf == 0) ? bias[c] : 0.0f;        // input bias (into xp)
    const float b1 = (hf == 0) ? bias[G3 + c] : 0.0f;   // recurrent bias

    // head weights (wave 0 only uses them)
    float dwv[8];
    float dbv = 0.0f;
    if (w == 0) {
        const int e = j & 7;
#pragma unroll
        for (int i = 0; i < 8; ++i) dwv[i] = dw[e * 8 + i];
        dbv = db[0];
    } else {
#pragma unroll
        for (int i = 0; i < 8; ++i) dwv[i] = 0.0f;
    }

    const int len = lengths[b];
    const float* vbp = values + (size_t)b * TQ * FQ;
    float* ob = out + (size_t)b * TQ;

    // zero the s_v pads (uninit LDS could be NaN; NaN*0 = NaN)
    if (tid < 2 * CH * 3) {
        int bb = tid / (CH * 3), rem = tid % (CH * 3);
        s_v[bb][rem / 3][37 + rem % 3] = 0.0f;
    }

    // ---- prologue: stage chunk0 -> s_v[0]; issue chunk1; xp(chunk0) ----
    const int srow = tid / FQ, scol = tid - srow * FQ;
    const bool st_act = tid < CH * FQ;
    float stage = 0.0f;
    if (st_act) stage = vbp[srow * FQ + scol];
    asm volatile("s_waitcnt vmcnt(0)" ::: "memory");
    if (st_act) s_v[0][srow][scol] = stage;
    if (st_act) stage = vbp[(CH + srow) * FQ + scol];   // chunk 1
    asm volatile("s_waitcnt lgkmcnt(0)" ::: "memory");
    __builtin_amdgcn_s_barrier();                        // s_v[0] visible

#define SLICE(SV, DP, ROW)                                                  \
    {                                                                       \
        const float4* vr = (const float4*)&s_v[SV][ROW][hf * 20];           \
        float4 v0 = vr[0], v1 = vr[1], v2 = vr[2], v3 = vr[3], v4 = vr[4];  \
        float a0 = b0, a1 = 0.0f;                                           \
        a0 += v0.x * Kc[0];  a1 += v0.y * Kc[1];                            \
        a0 += v0.z * Kc[2];  a1 += v0.w * Kc[3];                            \
        a0 += v1.x * Kc[4];  a1 += v1.y * Kc[5];                            \
        a0 += v1.z * Kc[6];  a1 += v1.w * Kc[7];                            \
        a0 += v2.x * Kc[8];  a1 += v2.y * Kc[9];                            \
        a0 += v2.z * Kc[10]; a1 += v2.w * Kc[11];                           \
        a0 += v3.x * Kc[12]; a1 += v3.y * Kc[13];                           \
        a0 += v3.z * Kc[14]; a1 += v3.w * Kc[15];                           \
        a0 += v4.x * Kc[16]; a1 += v4.y * Kc[17];                           \
        a0 += v4.z * Kc[18]; a1 += v4.w * Kc[19];                           \
        s_xpp[DP][hf][ROW][c] = a0 + a1;                                    \
    }

    // xp for chunk 0 -> s_xpp[0]
#pragma unroll
    for (int s = 0; s < CH; ++s) SLICE(0, 0, s)
    // (visibility of s_xpp[0] covered by the t=0 boundary barrier below)

    float h = 0.0f;                        // lane j holds h_j, in EVERY wave

    for (int t = 0; t < TQ; ++t) {
        const int tc  = t & (CH - 1);
        const int buf = t & 1;
        const int par = (t >> 3) & 1;

        if (tc == 0) {
            // stage(ck+1) arrived; drains head out-stores too
            asm volatile("s_waitcnt vmcnt(0)" ::: "memory");
            if (st_act) s_v[par ^ 1][srow][scol] = stage;
            if (st_act && (t + 2 * CH) < TQ)
                stage = vbp[(t + 2 * CH + srow) * FQ + scol];   // chunk ck+2
            asm volatile("s_waitcnt lgkmcnt(0)" ::: "memory");
            __builtin_amdgcn_s_barrier();

            // head for previous chunk (wave 0; reads its OWN s_h8 writes)
            if (w == 0 && t >= CH) {
                const int e = j & 7, s = j >> 3;
                const float4* hr = (const float4*)&s_h8[s][e * 8];
                float4 ha = hr[0], hb4 = hr[1];
                float p = ha.x * dwv[0] + ha.y * dwv[1] + ha.z * dwv[2] + ha.w * dwv[3]
                        + hb4.x * dwv[4] + hb4.y * dwv[5] + hb4.z * dwv[6] + hb4.w * dwv[7];
                p += __shfl_xor(p, 1, 64);
                p += __shfl_xor(p, 2, 64);
                p += __shfl_xor(p, 4, 64);
                if (e == 0) ob[t - CH + s] = sigmoid_f(p + dbv);
            }
        }

        // ---- phase A: half-GEMV via readlane broadcast of register h ----
        float p0 = 0.f, p1 = 0.f, p2 = 0.f, p3 = 0.f;
        const int hbits = __float_as_int(h);
        if (hf == 0) {
#pragma unroll
            for (int i = 0; i < 32; i += 4) {
                p0 += __int_as_float(__builtin_amdgcn_readlane(hbits, i + 0)) * Rc[i + 0];
                p1 += __int_as_float(__builtin_amdgcn_readlane(hbits, i + 1)) * Rc[i + 1];
                p2 += __int_as_float(__builtin_amdgcn_readlane(hbits, i + 2)) * Rc[i + 2];
                p3 += __int_as_float(__builtin_amdgcn_readlane(hbits, i + 3)) * Rc[i + 3];
            }
        } else {
#pragma unroll
            for (int i = 0; i < 32; i += 4) {
                p0 += __int_as_float(__builtin_amdgcn_readlane(hbits, 32 + i + 0)) * Rc[i + 0];
                p1 += __int_as_float(__builtin_amdgcn_readlane(hbits, 32 + i + 1)) * Rc[i + 1];
                p2 += __int_as_float(__builtin_amdgcn_readlane(hbits, 32 + i + 2)) * Rc[i + 2];
                p3 += __int_as_float(__builtin_amdgcn_readlane(hbits, 32 + i + 3)) * Rc[i + 3];
            }
        }
        float partial = (p0 + p1) + (p2 + p3);

        float xh = 0.0f;
        if (hf == 0) {
            partial += b1;
            const float xps = s_xpp[par][0][tc][c] + s_xpp[par][1][tc][c];
            if (g < 2) partial += xps;     // fold x-part into z, r partials
            else       xh = xps;           // h-gate: keep x-part separate
        }
        s_part[buf][g * 2 + hf][j] = partial;
        if (g == 2 && hf == 0) s_part[buf][6][j] = xh;

        // ---- slice: 1/8 of NEXT chunk's xp (off the dependency chain) ----
        SLICE(par ^ 1, par ^ 1, tc)

        asm volatile("s_waitcnt lgkmcnt(0)" ::: "memory");
        __builtin_amdgcn_s_barrier();

        // ---- phase B: gates + update, redundant on all 6 waves ----
        const float z  = sigmoid_f(s_part[buf][0][j] + s_part[buf][1][j]);
        const float r  = sigmoid_f(s_part[buf][2][j] + s_part[buf][3][j]);
        const float hh = s_part[buf][4][j] + s_part[buf][5][j];
        const float xg = s_part[buf][6][j];
        const float cc = tanh_f(xg + r * hh);
        const float hn = z * h + (1.0f - z) * cc;
        h = (t < len) ? hn : h;            // Keras masking (len uniform per block)

        if (w == 0) s_h8[tc][j] = h;       // stage for head (same-wave reads)
    }

    // epilogue: head for the last chunk
    if (w == 0) {
        const int e = j & 7, s = j >> 3;
        asm volatile("s_waitcnt lgkmcnt(0)" ::: "memory");
        const float4* hr = (const float4*)&s_h8[s][e * 8];
        float4 ha = hr[0], hb4 = hr[1];
        float p = ha.x * dwv[0] + ha.y * dwv[1] + ha.z * dwv[2] + ha.w * dwv[3]
                + hb4.x * dwv[4] + hb4.y * dwv[5] + hb4.z * dwv[6] + hb4.w * dwv[7];
        p += __shfl_xor(p, 1, 64);
        p += __shfl_xor(p, 2, 64);
        p += __shfl_xor(p, 4, 64);
        if (e == 0) ob[TQ - CH + s] = sigmoid_f(p + dbv);
    }
#undef SLICE
}

extern "C" void kernel_launch(void* const* d_in, const int* in_sizes, int n_in,
                              void* d_out, int out_size, void* d_ws, size_t ws_size,
                              hipStream_t stream) {
    const float* values  = (const float*)d_in[2];
    const int*   lengths = (const int*)  d_in[4];
    const float* Wk      = (const float*)d_in[5];
    const float* Wr      = (const float*)d_in[6];
    const float* bias    = (const float*)d_in[7];
    const float* dw      = (const float*)d_in[8];
    const float* db      = (const float*)d_in[9];
    float* out = (float*)d_out;

    gru_rec<<<dim3(BQ), dim3(BLK), 0, stream>>>(
        values, lengths, Wk, Wr, bias, dw, db, out);
}

// Round 6
// 747.126 us; speedup vs baseline: 1.5461x; 1.0289x over previous
//
#include <hip/hip_runtime.h>

#define BQ 256
#define TQ 1024
#define FQ 37
#define UQ 64
#define G3 192
#define CH 8
#define NCK (TQ / CH)   // 128 chunks

__device__ __forceinline__ float sigmoid_f(float x) {
    return 1.0f / (1.0f + __expf(-x));
}
__device__ __forceinline__ float tanh_f(float x) {
    return 1.0f - 2.0f / (__expf(2.0f * x) + 1.0f);
}

// 2 waves per block (one batch element), producer/consumer:
//  wave0 (consumer): whole recurrence, lane j owns h_j and gate columns
//        j / 64+j / 128+j  -> step update is LANE-LOCAL, no exchange.
//        Per step: 64 readlane (h broadcast to SGPRs) + 192 fma + gates.
//  wave1 (producer): stages values, computes x-projections one chunk ahead,
//        dense(1)+sigmoid head for the previous chunk.
//  Sync: ONE s_barrier per 8 steps. No per-step barriers, no vmcnt in the
//  recurrence wave's path, ever.
// amdgpu_waves_per_eu(1,1): occupancy pinned to 1 wave/EU so the allocator
// has no occupancy motive to cap VGPRs (R1/R3 showed it caps at 64 and
// spills the ~300 resident weights otherwise).
__global__ __launch_bounds__(128)
__attribute__((amdgpu_waves_per_eu(1, 1)))
void gru_pc(const float* __restrict__ values,   // [B,T,F]
            const int*   __restrict__ lengths,  // [B]
            const float* __restrict__ Wk,       // [F,3U]
            const float* __restrict__ Wr,       // [U,3U]
            const float* __restrict__ bias,     // [2,3U]
            const float* __restrict__ dw,       // [U]
            const float* __restrict__ db,       // [1]
            float*       __restrict__ out)      // [B,T]
{
    const int tid = threadIdx.x;
    const int j   = tid & 63;
    const int w   = tid >> 6;
    const int b   = blockIdx.x;

    __shared__ __align__(16) float s_v[2][CH][40];   // staged values (dbuf)
    __shared__ float s_xp[2][CH][G3];                // x-projections (dbuf)
    __shared__ __align__(16) float s_h8[2][CH][76];  // h history (pad: bank-spread)

    const float* vbp = values + (size_t)b * TQ * FQ;
    float* ob = out + (size_t)b * TQ;

    // ---------------- wave-0 state (recurrence) ----------------
    float Rz[UQ], Rr[UQ], Rh[UQ];
    float b1z = 0.f, b1r = 0.f, b1h = 0.f;
    int len = 0;
    // ---------------- wave-1 state (producer) ------------------
    float Kz[FQ], Kr[FQ], Kh[FQ];
    float b0z = 0.f, b0r = 0.f, b0h = 0.f, dbv = 0.f;
    float dwv[8];
    float stg[5];
    int rq[5], cq[5];

// x-projection for one staged row: lane j -> columns j, 64+j, 128+j
#define XPROW(PB, ROW)                                                       \
    {                                                                        \
        const float4* vr = (const float4*)&s_v[PB][ROW][0];                  \
        float vv[36];                                                        \
        *(float4*)&vv[0]  = vr[0]; *(float4*)&vv[4]  = vr[1];                \
        *(float4*)&vv[8]  = vr[2]; *(float4*)&vv[12] = vr[3];                \
        *(float4*)&vv[16] = vr[4]; *(float4*)&vv[20] = vr[5];                \
        *(float4*)&vv[24] = vr[6]; *(float4*)&vv[28] = vr[7];                \
        *(float4*)&vv[32] = vr[8];                                           \
        const float v36 = s_v[PB][ROW][36];                                  \
        float az = b0z, ar = b0r, ah = b0h;                                  \
        _Pragma("unroll")                                                    \
        for (int f = 0; f < 36; ++f) {                                       \
            az += vv[f] * Kz[f];                                             \
            ar += vv[f] * Kr[f];                                             \
            ah += vv[f] * Kh[f];                                             \
        }                                                                    \
        az += v36 * Kz[36]; ar += v36 * Kr[36]; ah += v36 * Kh[36];          \
        s_xp[PB][ROW][j]       = az;                                         \
        s_xp[PB][ROW][64 + j]  = ar;                                         \
        s_xp[PB][ROW][128 + j] = ah;                                         \
    }

#define HEAD(HB, TB)                                                         \
    {                                                                        \
        const int e = j & 7, s = j >> 3;                                     \
        const float4* hr = (const float4*)&s_h8[HB][s][e * 8];               \
        float4 ha = hr[0], hc = hr[1];                                       \
        float p = ha.x * dwv[0] + ha.y * dwv[1] + ha.z * dwv[2]              \
                + ha.w * dwv[3] + hc.x * dwv[4] + hc.y * dwv[5]              \
                + hc.z * dwv[6] + hc.w * dwv[7];                             \
        p += __shfl_xor(p, 1, 64);                                           \
        p += __shfl_xor(p, 2, 64);                                           \
        p += __shfl_xor(p, 4, 64);                                           \
        if (e == 0) ob[(TB) + s] = sigmoid_f(p + dbv);                       \
    }

    if (w == 0) {
#pragma unroll
        for (int u = 0; u < UQ; ++u) {
            Rz[u] = Wr[u * G3 + j];
            Rr[u] = Wr[u * G3 + 64 + j];
            Rh[u] = Wr[u * G3 + 128 + j];
        }
        b1z = bias[G3 + j];
        b1r = bias[G3 + 64 + j];
        b1h = bias[G3 + 128 + j];
        len = lengths[b];
    } else {
#pragma unroll
        for (int f = 0; f < FQ; ++f) {
            Kz[f] = Wk[f * G3 + j];
            Kr[f] = Wk[f * G3 + 64 + j];
            Kh[f] = Wk[f * G3 + 128 + j];
        }
        b0z = bias[j];
        b0r = bias[64 + j];
        b0h = bias[128 + j];
        dbv = db[0];
        const int e = j & 7;
#pragma unroll
        for (int i = 0; i < 8; ++i) dwv[i] = dw[e * 8 + i];
#pragma unroll
        for (int q = 0; q < 5; ++q) {
            const int idx = j + 64 * q;
            rq[q] = idx / FQ;
            cq[q] = idx - rq[q] * FQ;
        }
        // ---- prologue: stage chunk 0, issue chunk 1, xp(chunk 0) ----
#pragma unroll
        for (int q = 0; q < 5; ++q) {
            const int idx = j + 64 * q;
            stg[q] = (idx < CH * FQ) ? vbp[idx] : 0.0f;
        }
        asm volatile("s_waitcnt vmcnt(0)" ::: "memory");
#pragma unroll
        for (int q = 0; q < 5; ++q)
            if (j + 64 * q < CH * FQ) s_v[0][rq[q]][cq[q]] = stg[q];
#pragma unroll
        for (int q = 0; q < 5; ++q) {
            const int idx = j + 64 * q;
            if (idx < CH * FQ) stg[q] = vbp[CH * FQ + idx];
        }
        asm volatile("s_waitcnt lgkmcnt(0)" ::: "memory");  // s_v[0] visible to me
#pragma unroll 1
        for (int s = 0; s < CH; ++s) XPROW(0, s)
    }
    asm volatile("s_waitcnt lgkmcnt(0)" ::: "memory");
    __builtin_amdgcn_s_barrier();      // xp[0] + weights visible

    float h = 0.0f;                    // wave0: lane j holds h_j

#pragma unroll 1
    for (int k = 0; k < NCK; ++k) {
        const int pb = k & 1;
        if (w == 0) {
            const int tbase = k * CH;
#pragma unroll 1
            for (int tc = 0; tc < CH; ++tc) {
                const float xz = s_xp[pb][tc][j];
                const float xr = s_xp[pb][tc][64 + j];
                const float xh = s_xp[pb][tc][128 + j];
                const int hbits = __float_as_int(h);
                float az0 = 0.f, az1 = 0.f, ar0 = 0.f, ar1 = 0.f,
                      ah0 = 0.f, ah1 = 0.f;
#pragma unroll
                for (int u = 0; u < UQ; u += 2) {
                    const float h0 = __int_as_float(
                        __builtin_amdgcn_readlane(hbits, u));
                    const float h1 = __int_as_float(
                        __builtin_amdgcn_readlane(hbits, u + 1));
                    az0 += h0 * Rz[u];     az1 += h1 * Rz[u + 1];
                    ar0 += h0 * Rr[u];     ar1 += h1 * Rr[u + 1];
                    ah0 += h0 * Rh[u];     ah1 += h1 * Rh[u + 1];
                }
                const float z  = sigmoid_f(xz + b1z + (az0 + az1));
                const float r  = sigmoid_f(xr + b1r + (ar0 + ar1));
                const float cc = tanh_f(xh + r * (b1h + (ah0 + ah1)));
                const float hn = z * h + (1.0f - z) * cc;
                h = ((tbase + tc) < len) ? hn : h;
                s_h8[pb][tc][j] = h;
            }
        } else {
            if (k > 0) HEAD((k - 1) & 1, (k - 1) * CH)     // head, prev chunk
            if (k + 1 < NCK) {
                // staged loads (issued last chunk) -> LDS
                asm volatile("s_waitcnt vmcnt(0)" ::: "memory");
                const int nb = (k + 1) & 1;
#pragma unroll
                for (int q = 0; q < 5; ++q)
                    if (j + 64 * q < CH * FQ) s_v[nb][rq[q]][cq[q]] = stg[q];
                if (k + 2 < NCK) {                          // issue chunk k+2
#pragma unroll
                    for (int q = 0; q < 5; ++q) {
                        const int idx = j + 64 * q;
                        if (idx < CH * FQ)
                            stg[q] = vbp[(k + 2) * (CH * FQ) + idx];
                    }
                }
                asm volatile("s_waitcnt lgkmcnt(0)" ::: "memory");
#pragma unroll 1
                for (int s = 0; s < CH; ++s) XPROW(nb, s)
            }
        }
        asm volatile("s_waitcnt lgkmcnt(0)" ::: "memory");
        __builtin_amdgcn_s_barrier();   // once per 8 steps
    }

    if (w == 1) HEAD((NCK - 1) & 1, (NCK - 1) * CH)         // last chunk's head

#undef XPROW
#undef HEAD
}

extern "C" void kernel_launch(void* const* d_in, const int* in_sizes, int n_in,
                              void* d_out, int out_size, void* d_ws, size_t ws_size,
                              hipStream_t stream) {
    const float* values  = (const float*)d_in[2];
    const int*   lengths = (const int*)  d_in[4];
    const float* Wk      = (const float*)d_in[5];
    const float* Wr      = (const float*)d_in[6];
    const float* bias    = (const float*)d_in[7];
    const float* dw      = (const float*)d_in[8];
    const float* db      = (const float*)d_in[9];
    float* out = (float*)d_out;

    gru_pc<<<dim3(BQ), dim3(128), 0, stream>>>(
        values, lengths, Wk, Wr, bias, dw, db, out);
}